// Round 7
// baseline (350.376 us; speedup 1.0000x reference)
//
#include <hip/hip_runtime.h>

// Two-layer cached GCN. Round 7:
// (a) agg: 16 lanes/row, half8v (16B) gathers, x4 unroll -> 2x MLP
// (b) CSR build collapsed: per-bucket kernel does deg+scan+ofs+dinv+col fill
//     (replaces deg_bins + 3 scan kernels + fill_bins)
// (c) atomic-chain shrink: bincount merge with 64 blocks (chain 256->64),
//     binfill chunks 8192->12288 (chain 196->131), stageb dropped.

#define BKT_SHIFT 7
#define BKT_NODES 128
#define CH 12288
#define MAXBKT 1024

typedef _Float16 half4v __attribute__((ext_vector_type(4)));
typedef _Float16 half8v __attribute__((ext_vector_type(8)));
typedef float float4v __attribute__((ext_vector_type(4)));

// ---------------- bucket histogram (LDS-privatized, 64 blocks: short merge chains) ----------------
__global__ __launch_bounds__(256) void k_bincount(const int* __restrict__ dst,
                                                  int* __restrict__ bcnt, int E, int nbkt) {
    __shared__ int sh[MAXBKT];
    for (int i = threadIdx.x; i < nbkt; i += 256) sh[i] = 0;
    __syncthreads();
    for (long long e = (long long)blockIdx.x * 256 + threadIdx.x; e < E;
         e += (long long)gridDim.x * 256)
        atomicAdd(&sh[dst[e] >> BKT_SHIFT], 1);
    __syncthreads();
    for (int i = threadIdx.x; i < nbkt; i += 256)
        if (sh[i]) atomicAdd(&bcnt[i], sh[i]);
}

// ---------------- bucket scan (single block) ----------------
__global__ __launch_bounds__(1024) void k_bscan(const int* __restrict__ bcnt,
                                                int* __restrict__ bofs,
                                                int* __restrict__ bcur, int nbkt, int E) {
    __shared__ int sh[1024];
    int t = threadIdx.x;
    int v = (t < nbkt) ? bcnt[t] : 0;
    int x = v;
    sh[t] = x;
    __syncthreads();
    for (int o = 1; o < 1024; o <<= 1) {
        int y = (t >= o) ? sh[t - o] : 0;
        __syncthreads();
        x += y;
        sh[t] = x;
        __syncthreads();
    }
    if (t < nbkt) { bofs[t] = x - v; bcur[t] = x - v; }
    if (t == 0) bofs[nbkt] = E;
}

// ---------------- bulk-reservation bin fill ----------------
__global__ __launch_bounds__(256) void k_binfill(const int* __restrict__ src,
                                                 const int* __restrict__ dst,
                                                 int* __restrict__ bcur,
                                                 unsigned* __restrict__ recs,
                                                 int E, int nbkt) {
    __shared__ unsigned stage[CH];   // 48 KB
    __shared__ int cnt[MAXBKT];      // 4 KB
    __shared__ int base[MAXBKT];     // 4 KB
    const int t = threadIdx.x;
    const long long c0 = (long long)blockIdx.x * CH;

    for (int i = t; i < nbkt; i += 256) cnt[i] = 0;
    __syncthreads();

    // phase A: pack + stage + LDS histogram
    for (int k = 0; k < CH / 256; k++) {
        int i = k * 256 + t;
        long long e = c0 + i;
        if (e < E) {
            int d = dst[e];
            stage[i] = ((unsigned)(d & (BKT_NODES - 1)) << 17) | (unsigned)src[e];
            atomicAdd(&cnt[d >> BKT_SHIFT], 1);
        }
    }
    __syncthreads();

    // phase B: one global reservation per non-empty bucket
    for (int i = t; i < nbkt; i += 256) {
        int c = cnt[i];
        base[i] = c ? atomicAdd(&bcur[i], c) : 0;
        cnt[i] = 0;
    }
    __syncthreads();

    // phase C: scatter from LDS (bucket id re-derived from dst, L2-warm)
    for (int k = 0; k < CH / 256; k++) {
        int i = k * 256 + t;
        long long e = c0 + i;
        if (e < E) {
            int b = dst[e] >> BKT_SHIFT;
            int p = base[b] + atomicAdd(&cnt[b], 1);
            recs[p] = stage[i];
        }
    }
}

// ---------------- merged CSR: per-bucket deg + scan + ofs + dinv + col fill ----------------
__global__ __launch_bounds__(256) void k_csr_bins(const unsigned* __restrict__ recs,
                                                  const int* __restrict__ bofs,
                                                  float* __restrict__ dinv,
                                                  int* __restrict__ ofs,
                                                  int* __restrict__ col, int n, int E) {
    __shared__ int cnt[BKT_NODES];
    __shared__ int sh[256];
    __shared__ int cur[BKT_NODES];
    const int b = blockIdx.x, t = threadIdx.x;
    const int d0 = b << BKT_SHIFT;
    if (t < BKT_NODES) cnt[t] = 0;
    __syncthreads();
    const int beg = bofs[b], end = bofs[b + 1];
    for (int j = beg + t; j < end; j += 256)
        atomicAdd(&cnt[recs[j] >> 17], 1);
    __syncthreads();

    // 128-wide inclusive scan (padded to 256 threads)
    int v = (t < BKT_NODES) ? cnt[t] : 0;
    int x = v;
    sh[t] = x;
    __syncthreads();
    for (int o = 1; o < BKT_NODES; o <<= 1) {
        int y = (t >= o) ? sh[t - o] : 0;
        __syncthreads();
        x += y;
        sh[t] = x;
        __syncthreads();
    }

    if (t < BKT_NODES) {
        int node = d0 + t;
        if (node < n) {
            int o = beg + (x - v);          // exclusive prefix within bucket
            ofs[node] = o;
            cur[t] = o;
            dinv[node] = rsqrtf((float)v + 1.0f);  // +1 self-loop
        }
    }
    __syncthreads();

    for (int j = beg + t; j < end; j += 256) {
        unsigned r = recs[j];
        int p = atomicAdd(&cur[r >> 17], 1);
        col[p] = (int)(r & 0x1FFFF);
    }
    if (b == (int)gridDim.x - 1 && t == 0) ofs[n] = E;
}

// ---------------- W -> fp16 transposed, both layers in one kernel ----------------
__global__ __launch_bounds__(256) void k_wt2(const float* __restrict__ W1,
                                             const float* __restrict__ W2,
                                             _Float16* __restrict__ wt1,
                                             _Float16* __restrict__ wt2) {
    int i = blockIdx.x * 256 + threadIdx.x;   // 32768
    const float* W = (i < 16384) ? W1 : W2;
    _Float16* Wt = (i < 16384) ? wt1 : wt2;
    int j = i & 16383;
    int k = j >> 7, c = j & 127;
    Wt[c * 128 + k] = (_Float16)W[k * 128 + c];
}

// ---------------- MFMA GEMM: ts[N x 128](fp16) = dinv[row] * ((relu?)in @ W) ----------------
__global__ __launch_bounds__(256, 2) void k_gemm_mfma(const float* __restrict__ in,
                                                      const _Float16* __restrict__ Wt,
                                                      const float* __restrict__ dinv,
                                                      _Float16* __restrict__ out,
                                                      int n, int relu_in) {
    __shared__ _Float16 Al[64][136];
    __shared__ _Float16 Bl[128][136];
    const int t = threadIdx.x;
    const int row0 = blockIdx.x * 64;
    int nr = n - row0;
    if (nr > 64) nr = 64;

    for (int i = t; i < 128 * 16; i += 256) {
        int r = i >> 4, c8 = i & 15;
        *(half8v*)&Bl[r][c8 * 8] = *(const half8v*)&Wt[r * 128 + c8 * 8];
    }
    for (int i = t; i < nr * 32; i += 256) {
        int r = i >> 5, c4 = i & 31;
        float4 v = *(const float4*)&in[(size_t)(row0 + r) * 128 + c4 * 4];
        if (relu_in) {
            v.x = fmaxf(v.x, 0.f); v.y = fmaxf(v.y, 0.f);
            v.z = fmaxf(v.z, 0.f); v.w = fmaxf(v.w, 0.f);
        }
        half4v hv;
        hv[0] = (_Float16)v.x; hv[1] = (_Float16)v.y;
        hv[2] = (_Float16)v.z; hv[3] = (_Float16)v.w;
        *(half4v*)&Al[r][c4 * 4] = hv;
    }
    __syncthreads();

    const int wave = t >> 6;
    const int lane = t & 63;
    const int m0 = wave * 16;
    const int ml = lane & 15;
    const int quad = lane >> 4;

    float4v acc[8] = {};
#pragma unroll
    for (int kc = 0; kc < 4; kc++) {
        half8v a = *(const half8v*)&Al[m0 + ml][kc * 32 + quad * 8];
#pragma unroll
        for (int nt = 0; nt < 8; nt++) {
            half8v b = *(const half8v*)&Bl[nt * 16 + ml][kc * 32 + quad * 8];
            acc[nt] = __builtin_amdgcn_mfma_f32_16x16x32_f16(a, b, acc[nt], 0, 0, 0);
        }
    }

#pragma unroll
    for (int reg = 0; reg < 4; reg++) {
        int r = m0 + quad * 4 + reg;
        if (r < nr) {
            float dv = dinv[row0 + r];
#pragma unroll
            for (int nt = 0; nt < 8; nt++)
                out[(size_t)(row0 + r) * 128 + nt * 16 + ml] =
                    (_Float16)(acc[nt][reg] * dv);
        }
    }
}

// ---------------- CSR aggregation: 16 lanes/row, 16B gathers ----------------
// out[d] = bias + dinv[d] * (ts[d] + sum_j ts[col[j]])
__global__ __launch_bounds__(256) void k_agg_csr(const int* __restrict__ ofs,
                                                 const int* __restrict__ col,
                                                 const float* __restrict__ dinv,
                                                 const half8v* __restrict__ ts,  // rows = 16 half8
                                                 const float* __restrict__ bias,
                                                 float* __restrict__ out, int n) {
    int gid = blockIdx.x * 256 + threadIdx.x;
    int row = gid >> 4;
    int lane = gid & 15;
    if (row >= n) return;

    float dd = dinv[row];
    int beg = ofs[row];
    int end = ofs[row + 1];

    half8v sv = ts[(size_t)row * 16 + lane];
    float acc[8];
#pragma unroll
    for (int i = 0; i < 8; i++) acc[i] = (float)sv[i];

    int j = beg;
    for (; j + 3 < end; j += 4) {
        int s0 = col[j], s1 = col[j + 1], s2 = col[j + 2], s3 = col[j + 3];
        half8v v0 = ts[(size_t)s0 * 16 + lane];
        half8v v1 = ts[(size_t)s1 * 16 + lane];
        half8v v2 = ts[(size_t)s2 * 16 + lane];
        half8v v3 = ts[(size_t)s3 * 16 + lane];
#pragma unroll
        for (int i = 0; i < 8; i++)
            acc[i] += (float)v0[i] + (float)v1[i] + (float)v2[i] + (float)v3[i];
    }
    for (; j < end; j++) {
        half8v v = ts[(size_t)col[j] * 16 + lane];
#pragma unroll
        for (int i = 0; i < 8; i++) acc[i] += (float)v[i];
    }

    float4 b0 = *(const float4*)&bias[lane * 8];
    float4 b1 = *(const float4*)&bias[lane * 8 + 4];
    float4 o0, o1;
    o0.x = b0.x + dd * acc[0]; o0.y = b0.y + dd * acc[1];
    o0.z = b0.z + dd * acc[2]; o0.w = b0.w + dd * acc[3];
    o1.x = b1.x + dd * acc[4]; o1.y = b1.y + dd * acc[5];
    o1.z = b1.z + dd * acc[6]; o1.w = b1.w + dd * acc[7];
    *(float4*)&out[(size_t)row * 128 + lane * 8] = o0;
    *(float4*)&out[(size_t)row * 128 + lane * 8 + 4] = o1;
}

extern "C" void kernel_launch(void* const* d_in, const int* in_sizes, int n_in,
                              void* d_out, int out_size, void* d_ws, size_t ws_size,
                              hipStream_t stream) {
    const int N = in_sizes[0] / 128;
    const int E = in_sizes[1] / 2;
    const float* x  = (const float*)d_in[0];
    const int*   ei = (const int*)d_in[1];
    const float* W1 = (const float*)d_in[2];
    const float* b1 = (const float*)d_in[3];
    const float* W2 = (const float*)d_in[4];
    const float* b2 = (const float*)d_in[5];

    const int* src = ei;
    const int* dst = ei + E;

    const int NBKT = (N + BKT_NODES - 1) / BKT_NODES;

    // ---- workspace layout ----
    _Float16* t    = (_Float16*)d_ws;            // N*128
    _Float16* wt1  = t + (size_t)N * 128;        // 16384
    _Float16* wt2  = wt1 + 16384;                // 16384
    float*    dinv = (float*)(wt2 + 16384);      // N
    int*      ofs  = (int*)(dinv + N);           // N+1
    unsigned* recs = (unsigned*)(ofs + N + 1);   // E
    int*      col  = (int*)(recs + E);           // E
    int*      bofs = col + E;                    // NBKT+1
    int*      bcur = bofs + NBKT + 1;            // NBKT
    int*      bcnt = bcur + NBKT;                // NBKT

    float* h   = (float*)d_out;
    float* out = (float*)d_out;

    const int nb_g = (N + 63) / 64;
    const int nb_a = (int)(((long long)N * 16 + 255) / 256);
    const int nb_c = (int)(((long long)E + CH - 1) / CH);

    // ---- weight prep + binning + CSR build ----
    k_wt2<<<128, 256, 0, stream>>>(W1, W2, wt1, wt2);
    hipMemsetAsync(bcnt, 0, (size_t)NBKT * 4, stream);
    k_bincount<<<64, 256, 0, stream>>>(dst, bcnt, E, NBKT);
    k_bscan<<<1, 1024, 0, stream>>>(bcnt, bofs, bcur, NBKT, E);
    k_binfill<<<nb_c, 256, 0, stream>>>(src, dst, bcur, recs, E, NBKT);
    k_csr_bins<<<NBKT, 256, 0, stream>>>(recs, bofs, dinv, ofs, col, N, E);

    // ---- layer 1 ----
    k_gemm_mfma<<<nb_g, 256, 0, stream>>>(x, wt1, dinv, t, N, 0);
    k_agg_csr<<<nb_a, 256, 0, stream>>>(ofs, col, dinv, (const half8v*)t, b1, h, N);

    // ---- layer 2 ----
    k_gemm_mfma<<<nb_g, 256, 0, stream>>>(h, wt2, dinv, t, N, 1);
    k_agg_csr<<<nb_a, 256, 0, stream>>>(ofs, col, dinv, (const half8v*)t, b2, out, N);
}